// Round 1
// baseline (1369.253 us; speedup 1.0000x reference)
//
#include <hip/hip_runtime.h>
#include <hip/hip_bf16.h>

#define N_NODES 50000
#define N_EDGES 800000
#define D_FEAT 64

// SpMM via atomic scatter: each thread handles one edge x 4 consecutive
// features. 16 consecutive threads cover one edge's 64 features -> the
// x[src] row read is coalesced (float4/lane), src/dst/val broadcast from L1.
__global__ void spmm_atomic_kernel(const int* __restrict__ src,
                                   const int* __restrict__ dst,
                                   const float* __restrict__ val,
                                   const float* __restrict__ xin,
                                   float* __restrict__ out) {
    int t = blockIdx.x * blockDim.x + threadIdx.x;
    int e = t >> 4;
    if (e >= N_EDGES) return;
    int c = (t & 15) << 2;  // feature chunk offset [0,60]
    int s = src[e];
    int d = dst[e];
    float v = val[e];
    const float4 xv = *reinterpret_cast<const float4*>(xin + (long)s * D_FEAT + c);
    float* o = out + (long)d * D_FEAT + c;
    atomicAdd(o + 0, v * xv.x);
    atomicAdd(o + 1, v * xv.y);
    atomicAdd(o + 2, v * xv.z);
    atomicAdd(o + 3, v * xv.w);
}

// Per-node: logits = h @ W^T + b (2 classes), then 2-class log_softmax.
__global__ void fc_logsoftmax_kernel(const float* __restrict__ h,
                                     const float* __restrict__ w,
                                     const float* __restrict__ b,
                                     float* __restrict__ out) {
    int i = blockIdx.x * blockDim.x + threadIdx.x;
    if (i >= N_NODES) return;
    const float4* hr = reinterpret_cast<const float4*>(h + (long)i * D_FEAT);
    const float4* w0 = reinterpret_cast<const float4*>(w);
    const float4* w1 = reinterpret_cast<const float4*>(w + D_FEAT);
    float acc0 = 0.f, acc1 = 0.f;
#pragma unroll
    for (int k = 0; k < 16; ++k) {
        float4 hv = hr[k];
        float4 a = w0[k];
        float4 c = w1[k];
        acc0 += hv.x * a.x + hv.y * a.y + hv.z * a.z + hv.w * a.w;
        acc1 += hv.x * c.x + hv.y * c.y + hv.z * c.z + hv.w * c.w;
    }
    acc0 += b[0];
    acc1 += b[1];
    float m = fmaxf(acc0, acc1);
    float lse = m + logf(expf(acc0 - m) + expf(acc1 - m));
    out[(long)i * 2 + 0] = acc0 - lse;
    out[(long)i * 2 + 1] = acc1 - lse;
}

extern "C" void kernel_launch(void* const* d_in, const int* in_sizes, int n_in,
                              void* d_out, int out_size, void* d_ws, size_t ws_size,
                              hipStream_t stream) {
    const float* x        = (const float*)d_in[0];
    const int*   edge_src = (const int*)d_in[1];
    const int*   edge_dst = (const int*)d_in[2];
    const float* edge_val = (const float*)d_in[3];
    const float* fc_w     = (const float*)d_in[4];
    const float* fc_b     = (const float*)d_in[5];
    float* out = (float*)d_out;

    const size_t h_elems = (size_t)N_NODES * D_FEAT;
    float* h1 = (float*)d_ws;
    float* h2 = h1 + h_elems;

    // zero both hop accumulators (graph-capturable)
    hipMemsetAsync(d_ws, 0, 2 * h_elems * sizeof(float), stream);

    const int threads_spmm = N_EDGES * 16;
    const int blk = 256;
    dim3 grid_spmm((threads_spmm + blk - 1) / blk);

    // hop 1: h1 = A @ x
    spmm_atomic_kernel<<<grid_spmm, blk, 0, stream>>>(edge_src, edge_dst, edge_val, x, h1);
    // hop 2: h2 = A @ h1
    spmm_atomic_kernel<<<grid_spmm, blk, 0, stream>>>(edge_src, edge_dst, edge_val, h1, h2);

    // fc + log_softmax
    dim3 grid_fc((N_NODES + blk - 1) / blk);
    fc_logsoftmax_kernel<<<grid_fc, blk, 0, stream>>>(h2, fc_w, fc_b, out);
}

// Round 3
// 283.504 us; speedup vs baseline: 4.8297x; 4.8297x over previous
//
#include <hip/hip_runtime.h>
#include <hip/hip_bf16.h>

#define N_NODES 50000
#define N_EDGES 800000
#define D_FEAT 64

// ---------- CSR build ----------

__global__ void hist_kernel(const int* __restrict__ dst, int* __restrict__ cnt) {
    int e = blockIdx.x * blockDim.x + threadIdx.x;
    if (e >= N_EDGES) return;
    atomicAdd(&cnt[dst[e]], 1);
}

// Single-block exclusive scan of cnt[N_NODES] -> row_ptr[N_NODES+1], also
// initializes cursor[] = row_ptr[] for the scatter pass.
__global__ void scan_kernel(const int* __restrict__ cnt,
                            int* __restrict__ row_ptr,
                            int* __restrict__ cursor) {
    __shared__ int part[1024];
    const int t = threadIdx.x;
    const int CH = (N_NODES + 1023) / 1024;  // 49
    const int base = t * CH;
    int s = 0;
    for (int i = 0; i < CH; ++i) {
        int idx = base + i;
        if (idx < N_NODES) s += cnt[idx];
    }
    part[t] = s;
    __syncthreads();
    // Hillis-Steele inclusive scan over 1024 partials
    for (int off = 1; off < 1024; off <<= 1) {
        int v = (t >= off) ? part[t - off] : 0;
        __syncthreads();
        part[t] += v;
        __syncthreads();
    }
    int run = (t == 0) ? 0 : part[t - 1];  // exclusive prefix of this chunk
    for (int i = 0; i < CH; ++i) {
        int idx = base + i;
        if (idx < N_NODES) {
            row_ptr[idx] = run;
            cursor[idx]  = run;
            run += cnt[idx];
        }
    }
    if (t == 1023) row_ptr[N_NODES] = run;  // == N_EDGES
}

// Reorder edges into dst-major order: esrc_s/eval_s contiguous per dst row.
__global__ void scatter_kernel(const int* __restrict__ src,
                               const int* __restrict__ dst,
                               const float* __restrict__ val,
                               int* __restrict__ cursor,
                               int* __restrict__ esrc_s,
                               float* __restrict__ eval_s) {
    int e = blockIdx.x * blockDim.x + threadIdx.x;
    if (e >= N_EDGES) return;
    int d = dst[e];
    int pos = atomicAdd(&cursor[d], 1);
    esrc_s[pos] = src[e];
    eval_s[pos] = val[e];
}

// ---------- hop 1: gather SpMM ----------
// 16 lanes per node, float4 per lane (covers 64 feats). One streaming
// 256B row write per node; no atomics.
__global__ void spmm_gather_kernel(const int* __restrict__ row_ptr,
                                   const int* __restrict__ esrc,
                                   const float* __restrict__ eval,
                                   const float* __restrict__ xin,
                                   float* __restrict__ out) {
    int t = blockIdx.x * blockDim.x + threadIdx.x;
    int node = t >> 4;
    if (node >= N_NODES) return;
    int c = (t & 15) << 2;
    int beg = row_ptr[node];
    int end = row_ptr[node + 1];
    float4 acc = make_float4(0.f, 0.f, 0.f, 0.f);
    int j = beg;
    for (; j + 1 < end; j += 2) {
        int s0 = esrc[j], s1 = esrc[j + 1];
        float v0 = eval[j], v1 = eval[j + 1];
        const float4 x0 = *reinterpret_cast<const float4*>(xin + (long)s0 * D_FEAT + c);
        const float4 x1 = *reinterpret_cast<const float4*>(xin + (long)s1 * D_FEAT + c);
        acc.x += v0 * x0.x + v1 * x1.x;
        acc.y += v0 * x0.y + v1 * x1.y;
        acc.z += v0 * x0.z + v1 * x1.z;
        acc.w += v0 * x0.w + v1 * x1.w;
    }
    if (j < end) {
        int s0 = esrc[j];
        float v0 = eval[j];
        const float4 x0 = *reinterpret_cast<const float4*>(xin + (long)s0 * D_FEAT + c);
        acc.x += v0 * x0.x;
        acc.y += v0 * x0.y;
        acc.z += v0 * x0.z;
        acc.w += v0 * x0.w;
    }
    *reinterpret_cast<float4*>(out + (long)node * D_FEAT + c) = acc;
}

// ---------- hop 2 fused with FC + log_softmax ----------
// Same 16-lane gather, but instead of storing the 64-feat row, each lane
// reduces its float4 against the matching fc_w slices, then a 16-lane
// shuffle tree produces the two logits; lane 0 writes log_softmax.
__global__ void spmm_fc_fused_kernel(const int* __restrict__ row_ptr,
                                     const int* __restrict__ esrc,
                                     const float* __restrict__ eval,
                                     const float* __restrict__ xin,
                                     const float* __restrict__ w,
                                     const float* __restrict__ b,
                                     float* __restrict__ out) {
    int t = blockIdx.x * blockDim.x + threadIdx.x;
    int node = t >> 4;
    if (node >= N_NODES) return;
    int lane = t & 15;
    int c = lane << 2;
    int beg = row_ptr[node];
    int end = row_ptr[node + 1];
    float4 acc = make_float4(0.f, 0.f, 0.f, 0.f);
    int j = beg;
    for (; j + 1 < end; j += 2) {
        int s0 = esrc[j], s1 = esrc[j + 1];
        float v0 = eval[j], v1 = eval[j + 1];
        const float4 x0 = *reinterpret_cast<const float4*>(xin + (long)s0 * D_FEAT + c);
        const float4 x1 = *reinterpret_cast<const float4*>(xin + (long)s1 * D_FEAT + c);
        acc.x += v0 * x0.x + v1 * x1.x;
        acc.y += v0 * x0.y + v1 * x1.y;
        acc.z += v0 * x0.z + v1 * x1.z;
        acc.w += v0 * x0.w + v1 * x1.w;
    }
    if (j < end) {
        int s0 = esrc[j];
        float v0 = eval[j];
        const float4 x0 = *reinterpret_cast<const float4*>(xin + (long)s0 * D_FEAT + c);
        acc.x += v0 * x0.x;
        acc.y += v0 * x0.y;
        acc.z += v0 * x0.z;
        acc.w += v0 * x0.w;
    }
    // per-lane partial dot products with the two fc rows
    const float4 w0 = *reinterpret_cast<const float4*>(w + c);
    const float4 w1 = *reinterpret_cast<const float4*>(w + D_FEAT + c);
    float p0 = acc.x * w0.x + acc.y * w0.y + acc.z * w0.z + acc.w * w0.w;
    float p1 = acc.x * w1.x + acc.y * w1.y + acc.z * w1.z + acc.w * w1.w;
    // 16-lane reduction (nodes are 16-lane aligned within the wave)
#pragma unroll
    for (int off = 8; off >= 1; off >>= 1) {
        p0 += __shfl_down(p0, off, 16);
        p1 += __shfl_down(p1, off, 16);
    }
    if (lane == 0) {
        float acc0 = p0 + b[0];
        float acc1 = p1 + b[1];
        float m = fmaxf(acc0, acc1);
        float lse = m + logf(expf(acc0 - m) + expf(acc1 - m));
        out[(long)node * 2 + 0] = acc0 - lse;
        out[(long)node * 2 + 1] = acc1 - lse;
    }
}

extern "C" void kernel_launch(void* const* d_in, const int* in_sizes, int n_in,
                              void* d_out, int out_size, void* d_ws, size_t ws_size,
                              hipStream_t stream) {
    const float* x        = (const float*)d_in[0];
    const int*   edge_src = (const int*)d_in[1];
    const int*   edge_dst = (const int*)d_in[2];
    const float* edge_val = (const float*)d_in[3];
    const float* fc_w     = (const float*)d_in[4];
    const float* fc_b     = (const float*)d_in[5];
    float* out = (float*)d_out;

    const size_t h_elems = (size_t)N_NODES * D_FEAT;  // 3.2M floats = 12.8 MB
    float* h1      = (float*)d_ws;
    int*   cnt     = (int*)(h1 + h_elems);
    int*   row_ptr = cnt + N_NODES;
    int*   cursor  = row_ptr + (N_NODES + 1);
    int*   esrc_s  = cursor + N_NODES;
    float* eval_s  = (float*)(esrc_s + N_EDGES);
    // total ws use: 12.8MB + 0.2*3 MB + 3.2MB + 3.2MB ~= 19.8 MB

    const int blk = 256;

    // ---- CSR build (dst-major), reused by both hops ----
    hipMemsetAsync(cnt, 0, N_NODES * sizeof(int), stream);
    hist_kernel<<<(N_EDGES + blk - 1) / blk, blk, 0, stream>>>(edge_dst, cnt);
    scan_kernel<<<1, 1024, 0, stream>>>(cnt, row_ptr, cursor);
    scatter_kernel<<<(N_EDGES + blk - 1) / blk, blk, 0, stream>>>(
        edge_src, edge_dst, edge_val, cursor, esrc_s, eval_s);

    // ---- hop 1 ----
    const int threads_spmm = N_NODES * 16;
    dim3 grid_spmm((threads_spmm + blk - 1) / blk);
    spmm_gather_kernel<<<grid_spmm, blk, 0, stream>>>(row_ptr, esrc_s, eval_s, x, h1);

    // ---- hop 2 + fc + log_softmax (fused) ----
    spmm_fc_fused_kernel<<<grid_spmm, blk, 0, stream>>>(
        row_ptr, esrc_s, eval_s, h1, fc_w, fc_b, out);
}

// Round 4
// 161.826 us; speedup vs baseline: 8.4612x; 1.7519x over previous
//
#include <hip/hip_runtime.h>
#include <hip/hip_bf16.h>

#define N_NODES 50000
#define N_EDGES 800000
#define D_FEAT 64

#define SCAN_BLK 256
#define SCAN_GRID ((N_NODES + SCAN_BLK - 1) / SCAN_BLK)  // 196

// ---------- CSR build ----------

__global__ void hist_kernel(const int* __restrict__ dst, int* __restrict__ cnt) {
    int e = blockIdx.x * blockDim.x + threadIdx.x;
    if (e >= N_EDGES) return;
    atomicAdd(&cnt[dst[e]], 1);
}

// Level-1 scan: per-block LDS scan of 256 counts -> in-block exclusive
// prefix (pre) + block total (partials).
__global__ void scan_block_kernel(const int* __restrict__ cnt,
                                  int* __restrict__ pre,
                                  int* __restrict__ partials) {
    __shared__ int sm[SCAN_BLK];
    int i = blockIdx.x * SCAN_BLK + threadIdx.x;
    int v = (i < N_NODES) ? cnt[i] : 0;
    sm[threadIdx.x] = v;
    __syncthreads();
    for (int off = 1; off < SCAN_BLK; off <<= 1) {
        int t = (threadIdx.x >= (unsigned)off) ? sm[threadIdx.x - off] : 0;
        __syncthreads();
        sm[threadIdx.x] += t;
        __syncthreads();
    }
    if (i < N_NODES) pre[i] = sm[threadIdx.x] - v;
    if (threadIdx.x == SCAN_BLK - 1) partials[blockIdx.x] = sm[threadIdx.x];
}

// Level-2: single small block scans the 196 block partials.
__global__ void scan_partials_kernel(const int* __restrict__ partials,
                                     int* __restrict__ offsets) {
    __shared__ int sm[256];
    int t = threadIdx.x;
    int v = (t < SCAN_GRID) ? partials[t] : 0;
    sm[t] = v;
    __syncthreads();
    for (int off = 1; off < 256; off <<= 1) {
        int u = (t >= off) ? sm[t - off] : 0;
        __syncthreads();
        sm[t] += u;
        __syncthreads();
    }
    if (t < SCAN_GRID) offsets[t] = sm[t] - v;  // exclusive block offset
}

// Level-3: add block offsets -> row_ptr, cursor.
__global__ void finalize_kernel(const int* __restrict__ pre,
                                const int* __restrict__ offsets,
                                int* __restrict__ row_ptr,
                                int* __restrict__ cursor) {
    int i = blockIdx.x * SCAN_BLK + threadIdx.x;
    if (i < N_NODES) {
        int r = pre[i] + offsets[blockIdx.x];
        row_ptr[i] = r;
        cursor[i]  = r;
    }
    if (i == 0) row_ptr[N_NODES] = N_EDGES;
}

// Reorder edges into dst-major order.
__global__ void scatter_kernel(const int* __restrict__ src,
                               const int* __restrict__ dst,
                               const float* __restrict__ val,
                               int* __restrict__ cursor,
                               int* __restrict__ esrc_s,
                               float* __restrict__ eval_s) {
    int e = blockIdx.x * blockDim.x + threadIdx.x;
    if (e >= N_EDGES) return;
    int d = dst[e];
    int pos = atomicAdd(&cursor[d], 1);
    esrc_s[pos] = src[e];
    eval_s[pos] = val[e];
}

// ---------- hop 1: gather SpMM ----------
__global__ void spmm_gather_kernel(const int* __restrict__ row_ptr,
                                   const int* __restrict__ esrc,
                                   const float* __restrict__ eval,
                                   const float* __restrict__ xin,
                                   float* __restrict__ out) {
    int t = blockIdx.x * blockDim.x + threadIdx.x;
    int node = t >> 4;
    if (node >= N_NODES) return;
    int c = (t & 15) << 2;
    int beg = row_ptr[node];
    int end = row_ptr[node + 1];
    float4 acc = make_float4(0.f, 0.f, 0.f, 0.f);
    int j = beg;
    for (; j + 3 < end; j += 4) {
        int s0 = esrc[j], s1 = esrc[j + 1], s2 = esrc[j + 2], s3 = esrc[j + 3];
        float v0 = eval[j], v1 = eval[j + 1], v2 = eval[j + 2], v3 = eval[j + 3];
        const float4 x0 = *reinterpret_cast<const float4*>(xin + (long)s0 * D_FEAT + c);
        const float4 x1 = *reinterpret_cast<const float4*>(xin + (long)s1 * D_FEAT + c);
        const float4 x2 = *reinterpret_cast<const float4*>(xin + (long)s2 * D_FEAT + c);
        const float4 x3 = *reinterpret_cast<const float4*>(xin + (long)s3 * D_FEAT + c);
        acc.x += v0 * x0.x + v1 * x1.x + v2 * x2.x + v3 * x3.x;
        acc.y += v0 * x0.y + v1 * x1.y + v2 * x2.y + v3 * x3.y;
        acc.z += v0 * x0.z + v1 * x1.z + v2 * x2.z + v3 * x3.z;
        acc.w += v0 * x0.w + v1 * x1.w + v2 * x2.w + v3 * x3.w;
    }
    for (; j < end; ++j) {
        int s0 = esrc[j];
        float v0 = eval[j];
        const float4 x0 = *reinterpret_cast<const float4*>(xin + (long)s0 * D_FEAT + c);
        acc.x += v0 * x0.x;
        acc.y += v0 * x0.y;
        acc.z += v0 * x0.z;
        acc.w += v0 * x0.w;
    }
    *reinterpret_cast<float4*>(out + (long)node * D_FEAT + c) = acc;
}

// ---------- hop 2 fused with FC + log_softmax ----------
__global__ void spmm_fc_fused_kernel(const int* __restrict__ row_ptr,
                                     const int* __restrict__ esrc,
                                     const float* __restrict__ eval,
                                     const float* __restrict__ xin,
                                     const float* __restrict__ w,
                                     const float* __restrict__ b,
                                     float* __restrict__ out) {
    int t = blockIdx.x * blockDim.x + threadIdx.x;
    int node = t >> 4;
    if (node >= N_NODES) return;
    int lane = t & 15;
    int c = lane << 2;
    int beg = row_ptr[node];
    int end = row_ptr[node + 1];
    float4 acc = make_float4(0.f, 0.f, 0.f, 0.f);
    int j = beg;
    for (; j + 3 < end; j += 4) {
        int s0 = esrc[j], s1 = esrc[j + 1], s2 = esrc[j + 2], s3 = esrc[j + 3];
        float v0 = eval[j], v1 = eval[j + 1], v2 = eval[j + 2], v3 = eval[j + 3];
        const float4 x0 = *reinterpret_cast<const float4*>(xin + (long)s0 * D_FEAT + c);
        const float4 x1 = *reinterpret_cast<const float4*>(xin + (long)s1 * D_FEAT + c);
        const float4 x2 = *reinterpret_cast<const float4*>(xin + (long)s2 * D_FEAT + c);
        const float4 x3 = *reinterpret_cast<const float4*>(xin + (long)s3 * D_FEAT + c);
        acc.x += v0 * x0.x + v1 * x1.x + v2 * x2.x + v3 * x3.x;
        acc.y += v0 * x0.y + v1 * x1.y + v2 * x2.y + v3 * x3.y;
        acc.z += v0 * x0.z + v1 * x1.z + v2 * x2.z + v3 * x3.z;
        acc.w += v0 * x0.w + v1 * x1.w + v2 * x2.w + v3 * x3.w;
    }
    for (; j < end; ++j) {
        int s0 = esrc[j];
        float v0 = eval[j];
        const float4 x0 = *reinterpret_cast<const float4*>(xin + (long)s0 * D_FEAT + c);
        acc.x += v0 * x0.x;
        acc.y += v0 * x0.y;
        acc.z += v0 * x0.z;
        acc.w += v0 * x0.w;
    }
    const float4 w0 = *reinterpret_cast<const float4*>(w + c);
    const float4 w1 = *reinterpret_cast<const float4*>(w + D_FEAT + c);
    float p0 = acc.x * w0.x + acc.y * w0.y + acc.z * w0.z + acc.w * w0.w;
    float p1 = acc.x * w1.x + acc.y * w1.y + acc.z * w1.z + acc.w * w1.w;
#pragma unroll
    for (int off = 8; off >= 1; off >>= 1) {
        p0 += __shfl_down(p0, off, 16);
        p1 += __shfl_down(p1, off, 16);
    }
    if (lane == 0) {
        float acc0 = p0 + b[0];
        float acc1 = p1 + b[1];
        float m = fmaxf(acc0, acc1);
        float lse = m + logf(expf(acc0 - m) + expf(acc1 - m));
        out[(long)node * 2 + 0] = acc0 - lse;
        out[(long)node * 2 + 1] = acc1 - lse;
    }
}

extern "C" void kernel_launch(void* const* d_in, const int* in_sizes, int n_in,
                              void* d_out, int out_size, void* d_ws, size_t ws_size,
                              hipStream_t stream) {
    const float* x        = (const float*)d_in[0];
    const int*   edge_src = (const int*)d_in[1];
    const int*   edge_dst = (const int*)d_in[2];
    const float* edge_val = (const float*)d_in[3];
    const float* fc_w     = (const float*)d_in[4];
    const float* fc_b     = (const float*)d_in[5];
    float* out = (float*)d_out;

    const size_t h_elems = (size_t)N_NODES * D_FEAT;  // 3.2M floats
    float* h1       = (float*)d_ws;
    int*   cnt      = (int*)(h1 + h_elems);
    int*   pre      = cnt + N_NODES;
    int*   row_ptr  = pre + N_NODES;
    int*   cursor   = row_ptr + (N_NODES + 1);
    int*   partials = cursor + N_NODES;
    int*   offsets  = partials + SCAN_GRID;
    int*   esrc_s   = offsets + SCAN_GRID;
    float* eval_s   = (float*)(esrc_s + N_EDGES);
    // total ws use ~= 12.8 + 0.8 + 6.4 MB ~= 20 MB

    const int blk = 256;

    // ---- CSR build (dst-major), reused by both hops ----
    hipMemsetAsync(cnt, 0, N_NODES * sizeof(int), stream);
    hist_kernel<<<(N_EDGES + blk - 1) / blk, blk, 0, stream>>>(edge_dst, cnt);
    scan_block_kernel<<<SCAN_GRID, SCAN_BLK, 0, stream>>>(cnt, pre, partials);
    scan_partials_kernel<<<1, 256, 0, stream>>>(partials, offsets);
    finalize_kernel<<<SCAN_GRID, SCAN_BLK, 0, stream>>>(pre, offsets, row_ptr, cursor);
    scatter_kernel<<<(N_EDGES + blk - 1) / blk, blk, 0, stream>>>(
        edge_src, edge_dst, edge_val, cursor, esrc_s, eval_s);

    // ---- hop 1 ----
    const int threads_spmm = N_NODES * 16;
    dim3 grid_spmm((threads_spmm + blk - 1) / blk);
    spmm_gather_kernel<<<grid_spmm, blk, 0, stream>>>(row_ptr, esrc_s, eval_s, x, h1);

    // ---- hop 2 + fc + log_softmax (fused) ----
    spmm_fc_fused_kernel<<<grid_spmm, blk, 0, stream>>>(
        row_ptr, esrc_s, eval_s, h1, fc_w, fc_b, out);
}

// Round 6
// 139.396 us; speedup vs baseline: 9.8228x; 1.1609x over previous
//
#include <hip/hip_runtime.h>
#include <hip/hip_bf16.h>

#define N_NODES 50000
#define N_EDGES 800000
#define D_FEAT 64

#define SCAN_BLK 256
#define SCAN_GRID ((N_NODES + SCAN_BLK - 1) / SCAN_BLK)  // 196

// ---- bf16 helpers (manual, RNE) ----
__device__ __forceinline__ unsigned short f2b(float f) {
    unsigned int u = __float_as_uint(f);
    unsigned int lsb = (u >> 16) & 1u;
    u += 0x7fffu + lsb;
    return (unsigned short)(u >> 16);
}
// low bf16 of packed u32 -> float: u << 16 ; high bf16 -> float: u & 0xffff0000
__device__ __forceinline__ float blo(unsigned int u) { return __uint_as_float(u << 16); }
__device__ __forceinline__ float bhi(unsigned int u) { return __uint_as_float(u & 0xffff0000u); }

// ---------- x -> bf16 table ----------
__global__ void cvt_kernel(const float* __restrict__ x, unsigned short* __restrict__ xb) {
    int i = blockIdx.x * blockDim.x + threadIdx.x;  // one float4 per thread
    if (i >= (N_NODES * D_FEAT) / 4) return;
    float4 v = reinterpret_cast<const float4*>(x)[i];
    ushort4 o;
    o.x = f2b(v.x); o.y = f2b(v.y); o.z = f2b(v.z); o.w = f2b(v.w);
    reinterpret_cast<ushort4*>(xb)[i] = o;
}

// ---------- CSR build ----------
__global__ void hist_kernel(const int* __restrict__ dst, int* __restrict__ cnt) {
    int e = blockIdx.x * blockDim.x + threadIdx.x;
    if (e >= N_EDGES) return;
    atomicAdd(&cnt[dst[e]], 1);
}

__global__ void scan_block_kernel(const int* __restrict__ cnt,
                                  int* __restrict__ pre,
                                  int* __restrict__ partials) {
    __shared__ int sm[SCAN_BLK];
    int i = blockIdx.x * SCAN_BLK + threadIdx.x;
    int v = (i < N_NODES) ? cnt[i] : 0;
    sm[threadIdx.x] = v;
    __syncthreads();
    for (int off = 1; off < SCAN_BLK; off <<= 1) {
        int t = (threadIdx.x >= (unsigned)off) ? sm[threadIdx.x - off] : 0;
        __syncthreads();
        sm[threadIdx.x] += t;
        __syncthreads();
    }
    if (i < N_NODES) pre[i] = sm[threadIdx.x] - v;
    if (threadIdx.x == SCAN_BLK - 1) partials[blockIdx.x] = sm[threadIdx.x];
}

__global__ void scan_partials_kernel(const int* __restrict__ partials,
                                     int* __restrict__ offsets) {
    __shared__ int sm[256];
    int t = threadIdx.x;
    int v = (t < SCAN_GRID) ? partials[t] : 0;
    sm[t] = v;
    __syncthreads();
    for (int off = 1; off < 256; off <<= 1) {
        int u = (t >= off) ? sm[t - off] : 0;
        __syncthreads();
        sm[t] += u;
        __syncthreads();
    }
    if (t < SCAN_GRID) offsets[t] = sm[t] - v;
}

__global__ void finalize_kernel(const int* __restrict__ pre,
                                const int* __restrict__ offsets,
                                int* __restrict__ row_ptr,
                                int* __restrict__ cursor) {
    int i = blockIdx.x * SCAN_BLK + threadIdx.x;
    if (i < N_NODES) {
        int r = pre[i] + offsets[blockIdx.x];
        row_ptr[i] = r;
        cursor[i]  = r;
    }
    if (i == 0) row_ptr[N_NODES] = N_EDGES;
}

// Single packed 8B write per edge (halves random-write line-touches).
__global__ void scatter_kernel(const int* __restrict__ src,
                               const int* __restrict__ dst,
                               const float* __restrict__ val,
                               int* __restrict__ cursor,
                               int2* __restrict__ pack) {
    int e = blockIdx.x * blockDim.x + threadIdx.x;
    if (e >= N_EDGES) return;
    int d = dst[e];
    int pos = atomicAdd(&cursor[d], 1);
    int2 p;
    p.x = src[e];
    p.y = __float_as_int(val[e]);
    pack[pos] = p;
}

// ---------- hop 1: gather SpMM, bf16 in -> bf16 out ----------
// 8 lanes per node, 8 feats (16B uint4) per lane.
__global__ void spmm_gather_kernel(const int* __restrict__ row_ptr,
                                   const int2* __restrict__ pack,
                                   const unsigned short* __restrict__ xb,
                                   unsigned short* __restrict__ hb) {
    int t = blockIdx.x * blockDim.x + threadIdx.x;
    int node = t >> 3;
    if (node >= N_NODES) return;
    int c = (t & 7) << 3;  // feature offset 0..56
    int beg = row_ptr[node];
    int end = row_ptr[node + 1];
    float a0 = 0.f, a1 = 0.f, a2 = 0.f, a3 = 0.f, a4 = 0.f, a5 = 0.f, a6 = 0.f, a7 = 0.f;
    int j = beg;
    for (; j + 1 < end; j += 2) {
        int2 p0 = pack[j], p1 = pack[j + 1];
        float v0 = __int_as_float(p0.y), v1 = __int_as_float(p1.y);
        uint4 q0 = *reinterpret_cast<const uint4*>(xb + (long)p0.x * D_FEAT + c);
        uint4 q1 = *reinterpret_cast<const uint4*>(xb + (long)p1.x * D_FEAT + c);
        a0 += v0 * blo(q0.x) + v1 * blo(q1.x);
        a1 += v0 * bhi(q0.x) + v1 * bhi(q1.x);
        a2 += v0 * blo(q0.y) + v1 * blo(q1.y);
        a3 += v0 * bhi(q0.y) + v1 * bhi(q1.y);
        a4 += v0 * blo(q0.z) + v1 * blo(q1.z);
        a5 += v0 * bhi(q0.z) + v1 * bhi(q1.z);
        a6 += v0 * blo(q0.w) + v1 * blo(q1.w);
        a7 += v0 * bhi(q0.w) + v1 * bhi(q1.w);
    }
    if (j < end) {
        int2 p0 = pack[j];
        float v0 = __int_as_float(p0.y);
        uint4 q0 = *reinterpret_cast<const uint4*>(xb + (long)p0.x * D_FEAT + c);
        a0 += v0 * blo(q0.x); a1 += v0 * bhi(q0.x);
        a2 += v0 * blo(q0.y); a3 += v0 * bhi(q0.y);
        a4 += v0 * blo(q0.z); a5 += v0 * bhi(q0.z);
        a6 += v0 * blo(q0.w); a7 += v0 * bhi(q0.w);
    }
    uint4 o;
    o.x = (unsigned)f2b(a0) | ((unsigned)f2b(a1) << 16);
    o.y = (unsigned)f2b(a2) | ((unsigned)f2b(a3) << 16);
    o.z = (unsigned)f2b(a4) | ((unsigned)f2b(a5) << 16);
    o.w = (unsigned)f2b(a6) | ((unsigned)f2b(a7) << 16);
    *reinterpret_cast<uint4*>(hb + (long)node * D_FEAT + c) = o;
}

// ---------- hop 2 fused with FC + log_softmax ----------
__global__ void spmm_fc_fused_kernel(const int* __restrict__ row_ptr,
                                     const int2* __restrict__ pack,
                                     const unsigned short* __restrict__ hb,
                                     const float* __restrict__ w,
                                     const float* __restrict__ b,
                                     float* __restrict__ out) {
    int t = blockIdx.x * blockDim.x + threadIdx.x;
    int node = t >> 3;
    if (node >= N_NODES) return;
    int lane = t & 7;
    int c = lane << 3;
    int beg = row_ptr[node];
    int end = row_ptr[node + 1];
    float a0 = 0.f, a1 = 0.f, a2 = 0.f, a3 = 0.f, a4 = 0.f, a5 = 0.f, a6 = 0.f, a7 = 0.f;
    int j = beg;
    for (; j + 1 < end; j += 2) {
        int2 p0 = pack[j], p1 = pack[j + 1];
        float v0 = __int_as_float(p0.y), v1 = __int_as_float(p1.y);
        uint4 q0 = *reinterpret_cast<const uint4*>(hb + (long)p0.x * D_FEAT + c);
        uint4 q1 = *reinterpret_cast<const uint4*>(hb + (long)p1.x * D_FEAT + c);
        a0 += v0 * blo(q0.x) + v1 * blo(q1.x);
        a1 += v0 * bhi(q0.x) + v1 * bhi(q1.x);
        a2 += v0 * blo(q0.y) + v1 * blo(q1.y);
        a3 += v0 * bhi(q0.y) + v1 * bhi(q1.y);
        a4 += v0 * blo(q0.z) + v1 * blo(q1.z);
        a5 += v0 * bhi(q0.z) + v1 * bhi(q1.z);
        a6 += v0 * blo(q0.w) + v1 * blo(q1.w);
        a7 += v0 * bhi(q0.w) + v1 * bhi(q1.w);
    }
    if (j < end) {
        int2 p0 = pack[j];
        float v0 = __int_as_float(p0.y);
        uint4 q0 = *reinterpret_cast<const uint4*>(hb + (long)p0.x * D_FEAT + c);
        a0 += v0 * blo(q0.x); a1 += v0 * bhi(q0.x);
        a2 += v0 * blo(q0.y); a3 += v0 * bhi(q0.y);
        a4 += v0 * blo(q0.z); a5 += v0 * bhi(q0.z);
        a6 += v0 * blo(q0.w); a7 += v0 * bhi(q0.w);
    }
    // per-lane partial dots with the two fc rows (8 feats each)
    const float4 wa0 = *reinterpret_cast<const float4*>(w + c);
    const float4 wa1 = *reinterpret_cast<const float4*>(w + c + 4);
    const float4 wb0 = *reinterpret_cast<const float4*>(w + D_FEAT + c);
    const float4 wb1 = *reinterpret_cast<const float4*>(w + D_FEAT + c + 4);
    float p0 = a0 * wa0.x + a1 * wa0.y + a2 * wa0.z + a3 * wa0.w
             + a4 * wa1.x + a5 * wa1.y + a6 * wa1.z + a7 * wa1.w;
    float p1 = a0 * wb0.x + a1 * wb0.y + a2 * wb0.z + a3 * wb0.w
             + a4 * wb1.x + a5 * wb1.y + a6 * wb1.z + a7 * wb1.w;
#pragma unroll
    for (int off = 4; off >= 1; off >>= 1) {
        p0 += __shfl_down(p0, off, 8);
        p1 += __shfl_down(p1, off, 8);
    }
    if (lane == 0) {
        float acc0 = p0 + b[0];
        float acc1 = p1 + b[1];
        float m = fmaxf(acc0, acc1);
        float lse = m + logf(expf(acc0 - m) + expf(acc1 - m));
        out[(long)node * 2 + 0] = acc0 - lse;
        out[(long)node * 2 + 1] = acc1 - lse;
    }
}

extern "C" void kernel_launch(void* const* d_in, const int* in_sizes, int n_in,
                              void* d_out, int out_size, void* d_ws, size_t ws_size,
                              hipStream_t stream) {
    const float* x        = (const float*)d_in[0];
    const int*   edge_src = (const int*)d_in[1];
    const int*   edge_dst = (const int*)d_in[2];
    const float* edge_val = (const float*)d_in[3];
    const float* fc_w     = (const float*)d_in[4];
    const float* fc_b     = (const float*)d_in[5];
    float* out = (float*)d_out;

    const size_t tab_elems = (size_t)N_NODES * D_FEAT;  // 3.2M
    unsigned short* xb   = (unsigned short*)d_ws;                    // 6.4 MB
    unsigned short* hb   = xb + tab_elems;                           // 6.4 MB
    int2*           pack = (int2*)(hb + tab_elems);                  // 6.4 MB
    int* cnt      = (int*)(pack + N_EDGES);
    int* pre      = cnt + N_NODES;
    int* row_ptr  = pre + N_NODES;
    int* cursor   = row_ptr + (N_NODES + 1);
    int* partials = cursor + N_NODES;
    int* offsets  = partials + SCAN_GRID;
    // total ~= 19.2 MB + 0.8 MB

    const int blk = 256;

    // ---- CSR build + bf16 conversion ----
    hipMemsetAsync(cnt, 0, N_NODES * sizeof(int), stream);
    hist_kernel<<<(N_EDGES + blk - 1) / blk, blk, 0, stream>>>(edge_dst, cnt);
    cvt_kernel<<<((N_NODES * D_FEAT / 4) + blk - 1) / blk, blk, 0, stream>>>(x, xb);
    scan_block_kernel<<<SCAN_GRID, SCAN_BLK, 0, stream>>>(cnt, pre, partials);
    scan_partials_kernel<<<1, 256, 0, stream>>>(partials, offsets);
    finalize_kernel<<<SCAN_GRID, SCAN_BLK, 0, stream>>>(pre, offsets, row_ptr, cursor);
    scatter_kernel<<<(N_EDGES + blk - 1) / blk, blk, 0, stream>>>(
        edge_src, edge_dst, edge_val, cursor, pack);

    // ---- hop 1 (bf16 -> bf16) ----
    const int threads_spmm = N_NODES * 8;
    dim3 grid_spmm((threads_spmm + blk - 1) / blk);
    spmm_gather_kernel<<<grid_spmm, blk, 0, stream>>>(row_ptr, pack, xb, hb);

    // ---- hop 2 + fc + log_softmax (fused) ----
    spmm_fc_fused_kernel<<<grid_spmm, blk, 0, stream>>>(
        row_ptr, pack, hb, fc_w, fc_b, out);
}